// Round 8
// baseline (501.521 us; speedup 1.0000x reference)
//
#include <hip/hip_runtime.h>

#define BB 256
#define TT 1024
#define II 3
#define HH 128
#define OO 3
#define NT 576   // 8 compute waves (512 thr) + 1 store/projection wave (64 thr)

#if __has_builtin(__builtin_amdgcn_exp2f)
#define EXP2F __builtin_amdgcn_exp2f
#else
#define EXP2F exp2f
#endif
#if __has_builtin(__builtin_amdgcn_rcpf)
#define RCPF __builtin_amdgcn_rcpf
#else
#define RCPF(x) (1.0f / (x))
#endif

typedef __attribute__((ext_vector_type(2))) float f2;

// tanh(x) = 1 - 2/(e^{2x}+1)
__device__ __forceinline__ float fast_tanh(float x) {
    float e = EXP2F(x * 2.885390081777927f);
    return 1.0f - 2.0f * RCPF(e + 1.0f);
}

// Workgroup barrier that fences LDS only — does NOT drain vmcnt.
__device__ __forceinline__ void bar_lds() {
    asm volatile("s_waitcnt lgkmcnt(0)\n\ts_barrier" ::: "memory");
}

// packed fp32 FMA (CDNA gfx90a+): 2 FMAs in one instruction. The compiler
// does not form v_pk_fma_f32 from scalar fmaf; force it.
__device__ __forceinline__ f2 pk_fma(f2 a, f2 b, f2 c) {
    f2 d;
    asm("v_pk_fma_f32 %0, %1, %2, %3" : "=v"(d) : "v"(a), "v"(b), "v"(c));
    return d;
}

// x(lane ^ / rotated) via DPP (pure VALU)
template <int CTRL>
__device__ __forceinline__ float dpp_get(float x) {
    return __uint_as_float(__builtin_amdgcn_update_dpp(
        0, (int)__float_as_uint(x), CTRL, 0xF, 0xF, true));
}
template <int CTRL>
__device__ __forceinline__ float dpp_add(float p) { return p + dpp_get<CTRL>(p); }
#define DPP_XOR1 0xB1   // quad_perm [1,0,3,2]
#define DPP_XOR2 0x4E   // quad_perm [2,3,0,1]
#define DPP_ROR4 0x124  // row_ror:4  (16-lane row, preserves s&3)
#define DPP_ROR8 0x128  // row_ror:8

// sum over 4-lane quad via DPP quad_perm (store wave)
__device__ __forceinline__ float quad_reduce(float p) {
    p = dpp_add<DPP_XOR1>(p);
    p = dpp_add<DPP_XOR2>(p);
    return p;
}

// Physical storage permutation for the 128-float hidden state (float4-chunk
// granularity): logical chunk c (0..31) lives at physical chunk psi(c).
__device__ __forceinline__ int psi(int c) { return (c >> 1) | ((c & 1) << 4); }

// One block per batch element; one s_barrier per timestep (latency-bound).
//
// ROUND 8 CHANGE (VALU-instruction cut; structure frozen at round 6):
//  (1) 32 scalar FMAs -> 16 v_pk_fma_f32 (asm).
//  (2) reduce: butterfly-merge with selects. After per-lane 8-MAC partials
//      A0..A3 (outputs obase..obase+3, K-seg s): xor1 folds {A0,A1}->B and
//      {A2,A3}->C by parity (4 sel + 2 dpp-add); xor2 folds {B,C}->D by bit1
//      (2 sel + 1 dpp-add); D = quadsum of A_{s&3}. row_ror:8 + row_ror:4
//      rotation-sum the 4 quads (s&3 invariant) -> lane s holds the FULL sum
//      for output obase+(s&3). ~11 insts vs round 6's ~29.
//  Writers remain lanes s<4 (u==s&3==s), same psi slot; store wave untouched.
__global__ __launch_bounds__(NT, 1) void rnn_kernel(
    const float* __restrict__ x,     // [B,T,I]
    const float* __restrict__ Wih,   // [H,I]
    const float* __restrict__ Whh,   // [H,H]
    const float* __restrict__ bih,   // [H]
    const float* __restrict__ bhh,   // [H]
    const float* __restrict__ h0,    // [1,H]
    const float* __restrict__ Wout,  // [O,H]
    const float* __restrict__ bout,  // [O]
    float* __restrict__ out,         // [B,T,O]
    float* __restrict__ hid)         // [B,T,H]
{
    __shared__ __align__(16) float4 xs[TT];       // (x0,x1,x2,pad) per t
    __shared__ __align__(16) float hbuf[2][HH];   // double-buffered hidden (psi layout)
    __shared__ __align__(16) float psum[2][OO * 16];  // projection partials

    const int tid = threadIdx.x;
    const int b = blockIdx.x;

    // --- stage inputs; init h(0) in psi layout ---
    const float* xb = x + (size_t)b * TT * II;
    for (int idx = tid; idx < TT * II; idx += NT) {
        int t = idx / 3;
        int c = idx - t * 3;
        ((float*)&xs[t])[c] = xb[idx];
    }
    if (tid < HH) hbuf[0][4 * psi(tid >> 2) + (tid & 3)] = h0[tid];

    if (tid < 512) {
        // ================= compute waves =================
        const int lane = tid & 63;
        const int wv   = tid >> 6;       // wave 0..7
        const int og   = lane >> 4;      // output-group (16-lane DPP row) 0..3
        const int s    = lane & 15;      // K-segment: k in [8s, 8s+8)
        const int obase = wv * 16 + og * 4;
        const bool p0 = (s & 1) != 0;    // butterfly parity bits
        const bool p1 = (s & 2) != 0;

        // W_hh[obase+j][8s .. 8s+8] as f2 pairs (32 VGPRs)
        f2 wp[4][4];
#pragma unroll
        for (int j = 0; j < 4; ++j) {
            const float* wr = Whh + (size_t)(obase + j) * HH + 8 * s;
            float4 v1 = ((const float4*)wr)[0];
            float4 v2 = ((const float4*)wr)[1];
            wp[j][0] = f2{v1.x, v1.y};
            wp[j][1] = f2{v1.z, v1.w};
            wp[j][2] = f2{v2.x, v2.y};
            wp[j][3] = f2{v2.z, v2.w};
        }
        // every lane finishes output ru = obase + (s&3): its xp row
        const int ru = obase + (s & 3);
        const float wiu0 = Wih[ru * II + 0];
        const float wiu1 = Wih[ru * II + 1];
        const float wiu2 = Wih[ru * II + 2];
        const float biasu = bih[ru] + bhh[ru];
        // write slot for lanes s<4: logical h = obase+s
        const int wpos = 4 * psi(wv * 4 + og) + s;

        bar_lds();

        auto cstep = [&](int t, const float* hcur, float* hnext) {
            // logical h[8s..8s+8) through psi layout
            float4 h1 = ((const float4*)hcur)[s];
            float4 h2 = ((const float4*)hcur)[16 + s];
            f2 hh0 = f2{h1.x, h1.y}, hh1 = f2{h1.z, h1.w};
            f2 hh2 = f2{h2.x, h2.y}, hh3 = f2{h2.z, h2.w};
            // 4 outputs x 8 MACs = 16 v_pk_fma_f32 (4 indep chains of 4)
            f2 ac0 = f2{0.f, 0.f}, ac1 = f2{0.f, 0.f};
            f2 ac2 = f2{0.f, 0.f}, ac3 = f2{0.f, 0.f};
            ac0 = pk_fma(wp[0][0], hh0, ac0); ac0 = pk_fma(wp[0][1], hh1, ac0);
            ac0 = pk_fma(wp[0][2], hh2, ac0); ac0 = pk_fma(wp[0][3], hh3, ac0);
            ac1 = pk_fma(wp[1][0], hh0, ac1); ac1 = pk_fma(wp[1][1], hh1, ac1);
            ac1 = pk_fma(wp[1][2], hh2, ac1); ac1 = pk_fma(wp[1][3], hh3, ac1);
            ac2 = pk_fma(wp[2][0], hh0, ac2); ac2 = pk_fma(wp[2][1], hh1, ac2);
            ac2 = pk_fma(wp[2][2], hh2, ac2); ac2 = pk_fma(wp[2][3], hh3, ac2);
            ac3 = pk_fma(wp[3][0], hh0, ac3); ac3 = pk_fma(wp[3][1], hh1, ac3);
            ac3 = pk_fma(wp[3][2], hh2, ac3); ac3 = pk_fma(wp[3][3], hh3, ac3);
            float A0 = ac0.x + ac0.y, A1 = ac1.x + ac1.y;
            float A2 = ac2.x + ac2.y, A3 = ac3.x + ac3.y;
            // butterfly-merge reduce (selects fold acc count at each level)
            float s1 = p0 ? A1 : A0;
            float s2 = p0 ? A0 : A1;
            float B  = s1 + dpp_get<DPP_XOR1>(s2);   // pairsum of A_{p0}
            float c1 = p0 ? A3 : A2;
            float c2 = p0 ? A2 : A3;
            float C  = c1 + dpp_get<DPP_XOR1>(c2);   // pairsum of A_{2+p0}
            float d1 = p1 ? C : B;
            float d2 = p1 ? B : C;
            float D  = d1 + dpp_get<DPP_XOR2>(d2);   // quadsum of A_{s&3}
            D += dpp_get<DPP_ROR8>(D);               // + quads q+2
            D += dpp_get<DPP_ROR4>(D);               // + quads q+1,q+3 -> full
            // finish: xp + tanh for output obase+(s&3); lanes s<4 write
            float4 xv = xs[t];  // wave-uniform broadcast
            float xp = fmaf(xv.z, wiu2, fmaf(xv.y, wiu1, fmaf(xv.x, wiu0, biasu)));
            float val = fast_tanh(D + xp);
            if (s < 4) hnext[wpos] = val;
            bar_lds();
        };

        for (int t = 0; t < TT; t += 2) {
            cstep(t, hbuf[0], hbuf[1]);
            cstep(t + 1, hbuf[1], hbuf[0]);
        }
    } else {
        // ================= store + projection wave =================
        const int L = tid - 512;  // lane 0..63; owns logical h = 2L, 2L+1
        const float w00 = Wout[0 * HH + 2 * L], w01 = Wout[0 * HH + 2 * L + 1];
        const float w10 = Wout[1 * HH + 2 * L], w11 = Wout[1 * HH + 2 * L + 1];
        const float w20 = Wout[2 * HH + 2 * L], w21 = Wout[2 * HH + 2 * L + 1];
        const float bL = (L == 0) ? bout[0] : (L == 1) ? bout[1]
                       : (L == 2) ? bout[2] : 0.f;
        float* ob = out + (size_t)b * TT * OO;
        float* hb = hid + (size_t)b * TT * HH;
        const int q = L >> 2;               // quad id 0..15
        const bool qlead = (L & 3) == 0;
        // logical h[2L] through psi layout (float2-aligned)
        const int fpos = 4 * psi(L >> 1) + 2 * (L & 1);

        bar_lds();

        auto sstep = [&](int t, const float* hcur, float* psA, const float* psB) {
            // phase A: hid[t-1] store + quad partials for out[t-1] -> psA
            if (t >= 1) {
                const float2 hv = *(const float2*)(hcur + fpos);
                ((float2*)(hb + (size_t)(t - 1) * HH))[L] = hv;  // coalesced 512B
                float p0 = fmaf(hv.x, w00, hv.y * w01);
                float p1 = fmaf(hv.x, w10, hv.y * w11);
                float p2 = fmaf(hv.x, w20, hv.y * w21);
                p0 = quad_reduce(p0);
                p1 = quad_reduce(p1);
                p2 = quad_reduce(p2);
                if (qlead) {
                    psA[0 * 16 + q] = p0;
                    psA[1 * 16 + q] = p1;
                    psA[2 * 16 + q] = p2;
                }
            }
            // phase B: finish out[t-2] from previous window's partials (psB).
            if (t >= 2 && L < OO) {
                const float4* pp = (const float4*)(psB + L * 16);
                float4 u0 = pp[0], u1 = pp[1], u2 = pp[2], u3 = pp[3];
                float s0 = ((u0.x + u0.y) + (u0.z + u0.w)) +
                           ((u1.x + u1.y) + (u1.z + u1.w));
                float s1 = ((u2.x + u2.y) + (u2.z + u2.w)) +
                           ((u3.x + u3.y) + (u3.z + u3.w));
                ob[(size_t)(t - 2) * OO + L] = s0 + s1 + bL;
            }
            bar_lds();
        };

        for (int t = 0; t < TT; t += 2) {
            sstep(t, hbuf[0], psum[0], psum[1]);
            sstep(t + 1, hbuf[1], psum[1], psum[0]);
        }

        // tail (no barriers; compute waves exited, barrier counts match):
        // hbuf[0] = h[TT], psum[1] holds partials for out[TT-2].
        {
            const float2 hv = *(const float2*)(&hbuf[0][0] + fpos);
            ((float2*)(hb + (size_t)(TT - 1) * HH))[L] = hv;
            float p0 = fmaf(hv.x, w00, hv.y * w01);
            float p1 = fmaf(hv.x, w10, hv.y * w11);
            float p2 = fmaf(hv.x, w20, hv.y * w21);
            p0 = quad_reduce(p0);
            p1 = quad_reduce(p1);
            p2 = quad_reduce(p2);
            if (qlead) {
                psum[0][0 * 16 + q] = p0;
                psum[0][1 * 16 + q] = p1;
                psum[0][2 * 16 + q] = p2;
            }
            if (L < OO) {
                const float4* pp = (const float4*)(psum[1] + L * 16);
                float4 u0 = pp[0], u1 = pp[1], u2 = pp[2], u3 = pp[3];
                float s0 = ((u0.x + u0.y) + (u0.z + u0.w)) +
                           ((u1.x + u1.y) + (u1.z + u1.w));
                float s1 = ((u2.x + u2.y) + (u2.z + u2.w)) +
                           ((u3.x + u3.y) + (u3.z + u3.w));
                ob[(size_t)(TT - 2) * OO + L] = s0 + s1 + bL;
                const float4* pq = (const float4*)(psum[0] + L * 16);
                float4 v0 = pq[0], v1 = pq[1], v2 = pq[2], v3 = pq[3];
                float r0 = ((v0.x + v0.y) + (v0.z + v0.w)) +
                           ((v1.x + v1.y) + (v1.z + v1.w));
                float r1 = ((v2.x + v2.y) + (v2.z + v2.w)) +
                           ((v3.x + v3.y) + (v3.z + v3.w));
                ob[(size_t)(TT - 1) * OO + L] = r0 + r1 + bL;
            }
        }
    }
}

extern "C" void kernel_launch(void* const* d_in, const int* in_sizes, int n_in,
                              void* d_out, int out_size, void* d_ws, size_t ws_size,
                              hipStream_t stream) {
    const float* x    = (const float*)d_in[0];  // [256,1024,3]
    const float* Wih  = (const float*)d_in[1];  // [128,3]
    const float* Whh  = (const float*)d_in[2];  // [128,128]
    const float* bih  = (const float*)d_in[3];  // [128]
    const float* bhh  = (const float*)d_in[4];  // [128]
    const float* h0   = (const float*)d_in[5];  // [1,128]
    const float* Wout = (const float*)d_in[6];  // [3,128]
    const float* bout = (const float*)d_in[7];  // [3]

    float* out = (float*)d_out;                 // [B,T,O] first
    float* hid = out + (size_t)BB * TT * OO;    // then [B,T,H]

    rnn_kernel<<<BB, NT, 0, stream>>>(x, Wih, Whh, bih, bhh, h0, Wout, bout, out, hid);
}